// Round 10
// baseline (1042.386 us; speedup 1.0000x reference)
//
#include <hip/hip_runtime.h>
#include <math.h>

// Problem constants (PCUTransformer)
#define B_    8
#define L_    1000
#define F_    7
#define DM_   512
#define H_    8
#define DFF_  2048
#define NL_   4
#define PRED_ 50
#define DK_   64
#define P_    16
#define EPS_  1e-5f
#define QKVS  1792      // fused row: q(512) k(512) v-gap(512) qp(128) kp(128)

#define L2E_   1.4426950408889634f
#define C_QS   0.18033688011112042f   // 0.125 * log2(e) folded into q
#define BS_QP  2.8853900817779268f    // 2*log2(e) folded into fused qp weights
#define SHFT_  24.0f                  // fixed softmax shift (cancels in normalize)

typedef unsigned short u16;
typedef __bf16 bf16x8 __attribute__((ext_vector_type(8)));
typedef float  f32x4  __attribute__((ext_vector_type(4)));

// ---------------- helpers ----------------
__device__ inline float wave_reduce_sum(float x) {
#pragma unroll
  for (int off = 32; off >= 1; off >>= 1) x += __shfl_xor(x, off, 64);
  return x;
}
__device__ inline u16 f2bf(float f) {   // RNE float->bf16 bits
  unsigned int u = __float_as_uint(f);
  unsigned int r = u + 0x7FFFu + ((u >> 16) & 1u);
  return (u16)(r >> 16);
}
__device__ inline unsigned int pack2(float a, float b) {
  return (unsigned int)f2bf(a) | ((unsigned int)f2bf(b) << 16);
}
__device__ inline float bf2f(u16 u) { return __uint_as_float(((unsigned int)u) << 16); }
__device__ inline float fexp2(float x) { return __builtin_amdgcn_exp2f(x); }
__device__ inline float frcp(float x) { return __builtin_amdgcn_rcpf(x); }

union bfrag { bf16x8 b; uint4 q; u16 u[8]; };

// async global->LDS, 16B per lane; lds base wave-uniform, HW scatters lane*16
__device__ inline void gload16(const u16* g, u16* l) {
  __builtin_amdgcn_global_load_lds(
      (const __attribute__((address_space(1))) void*)g,
      (__attribute__((address_space(3))) void*)l, 16, 0, 0);
}

// ---------------- weight transpose-convert: out[n][k] = bf16(in[k][n]) ------
__global__ __launch_bounds__(256)
void transpose_w(const float* __restrict__ in, u16* __restrict__ out,
                 int K, int N, size_t in_lstride, size_t out_lstride,
                 int row_off, int out_ld) {
  __shared__ float tile[32][33];
  int z = blockIdx.z;
  int kk0 = blockIdx.y * 32, nn0 = blockIdx.x * 32;
  int tx = threadIdx.x & 31, ty = threadIdx.x >> 5;
  const float* ip = in + z * in_lstride;
  u16* op = out + z * out_lstride;
#pragma unroll
  for (int i = 0; i < 4; i++)
    tile[ty + i * 8][tx] = ip[(size_t)(kk0 + ty + i * 8) * N + nn0 + tx];
  __syncthreads();
#pragma unroll
  for (int i = 0; i < 4; i++)
    op[(size_t)(row_off + nn0 + ty + i * 8) * out_ld + kk0 + tx] = f2bf(tile[tx][ty + i * 8]);
}

// ---------------- fused lm weights: Wt rows 1536+side*128+hh*16+p -----------
__global__ __launch_bounds__(256)
void wfuse_kernel(const float* __restrict__ Wq, const float* __restrict__ Wk,
                  const float* __restrict__ lmqw, const float* __restrict__ lmkw,
                  u16* __restrict__ Wt) {
  int hh = blockIdx.x, side = blockIdx.y, layer = blockIdx.z;
  const float* W = (side ? Wk : Wq) + (size_t)layer * 512 * 512;
  const float* lw = side ? lmkw : lmqw;
  float scale = side ? 1.0f : BS_QP;
  __shared__ float lws[64][17];
  int t = threadIdx.x;
  for (int i = t; i < 1024; i += 256) lws[i >> 4][i & 15] = lw[i];
  __syncthreads();
  int p = t & 15, kk = t >> 4;
  u16* orow = Wt + (size_t)layer * QKVS * 512 + (size_t)(1536 + side * 128 + hh * 16 + p) * 512;
  for (int kb = 0; kb < 32; kb++) {
    int k = kb * 16 + kk;
    const float* wr = W + (size_t)k * 512 + hh * 64;
    float acc = 0.f;
#pragma unroll
    for (int d = 0; d < 64; d++) acc = fmaf(wr[d], lws[d][p], acc);
    orow[k] = f2bf(acc * scale);
  }
}

// ---------------- bias assembly: [NL][1792] ---------------------------------
__global__ __launch_bounds__(256)
void concat_bias(const float* __restrict__ bq, const float* __restrict__ bk,
                 const float* __restrict__ bv,
                 const float* __restrict__ lmqw, const float* __restrict__ lmqb,
                 const float* __restrict__ lmkw, const float* __restrict__ lmkb,
                 float* __restrict__ bqkv) {
  int i = blockIdx.x * 256 + threadIdx.x;   // NL*1792
  int l = i / QKVS, j = i % QKVS;
  float v;
  if (j < 512) v = bq[l * 512 + j];
  else if (j < 1024) v = bk[l * 512 + j - 512];
  else if (j < 1536) v = bv[l * 512 + j - 1024];
  else if (j < 1664) {
    int hh = (j - 1536) >> 4, p = (j - 1536) & 15;
    float acc = lmqb[p];
#pragma unroll
    for (int d = 0; d < 64; d++) acc = fmaf(bq[l * 512 + hh * 64 + d], lmqw[d * 16 + p], acc);
    v = acc * BS_QP;
  } else {
    int hh = (j - 1664) >> 4, p = (j - 1664) & 15;
    float acc = lmkb[p];
#pragma unroll
    for (int d = 0; d < 64; d++) acc = fmaf(bk[l * 512 + hh * 64 + d], lmkw[d * 16 + p], acc);
    v = acc;
  }
  bqkv[i] = v;
}

// ---------------- embedding (bf16 out) --------------------------------------
__global__ __launch_bounds__(512)
void embed_kernel(const float* __restrict__ x, const float* __restrict__ emb_w,
                  const float* __restrict__ emb_b, const float* __restrict__ pe,
                  u16* __restrict__ h16) {
  int bl = blockIdx.x;
  int l = bl % L_;
  int d = threadIdx.x;
  const float* xr = x + (size_t)bl * F_;
  float acc = emb_b[d] + pe[(size_t)l * DM_ + d];
#pragma unroll
  for (int f = 0; f < F_; f++) acc = fmaf(xr[f], emb_w[f * DM_ + d], acc);
  h16[(size_t)bl * DM_ + d] = f2bf(acc);
}

// ---------------- bf16 MFMA GEMM, BM=64, BK=32, LDS dbuf (R9, kept) ---------
// Occupancy fix verified: total 1118 -> 1033, all gemm dispatches < 58us.
template<int BN>
__global__ __launch_bounds__(256)
void gemm64(const u16* __restrict__ A, const u16* __restrict__ Bt,
            const float* __restrict__ bias, const u16* __restrict__ resid,
            u16* __restrict__ C16, u16* __restrict__ vtg,
            int M, int K, int N, int relu, int nscale, float sval) {
  constexpr int NTW = BN / 32;
  constexpr int BG  = BN / 64;          // B gloads per wave (128->2, 64->1)
  constexpr int ASZ = 32 * 64;          // 32 lines of 128B = 4KB per buffer
  constexpr int BSZ = (BN / 2) * 64;
  __shared__ u16 As[2 * ASZ];
  __shared__ u16 Bs[2 * BSZ];
  int t = threadIdx.x;
  int w = t >> 6, lane = t & 63;
  int wr = w >> 1, wc = w & 1;
  int mloc = lane & 15, quad = lane >> 4;
  int m0 = blockIdx.y * 64, n0 = blockIdx.x * BN;

  // staging: line R slot s holds chunk c=s^(R&7) -> global row 2R+(c>>2),
  // k-cols (c&3)*8..+8. Global addr carries the swizzle; LDS dest linear.
  const u16* agp; u16* alds;
  {
    int R = w * 8 + (lane >> 3);               // A line 0..31
    int c = (lane & 7) ^ (R & 7);
    int gm = m0 + 2 * R + (c >> 2); if (gm > M - 1) gm = M - 1;
    agp = A + (size_t)gm * K + (c & 3) * 8;
    alds = As + (w * 8) * 64;
  }
  const u16* bgp[BG]; u16* blds[BG];
#pragma unroll
  for (int j = 0; j < BG; j++) {
    int R = w * (8 * BG) + j * 8 + (lane >> 3); // B line 0..BN/2-1
    int c = (lane & 7) ^ (R & 7);
    bgp[j] = Bt + (size_t)(n0 + 2 * R + (c >> 2)) * K + (c & 3) * 8;
    blds[j] = Bs + (w * (8 * BG) + j * 8) * 64;
  }
  // fragment read: row tr, k-chunk quad -> line tr>>1, chunk (tr&1)*4+quad
  const u16* apt[2];
#pragma unroll
  for (int mi = 0; mi < 2; mi++) {
    int tr = wr * 32 + mi * 16 + mloc;
    int R = tr >> 1, c = (tr & 1) * 4 + quad;
    apt[mi] = As + R * 64 + ((c ^ (R & 7)) * 8);
  }
  const u16* bpt[NTW];
#pragma unroll
  for (int nt = 0; nt < NTW; nt++) {
    int tr = wc * (BN / 2) + nt * 16 + mloc;
    int R = tr >> 1, c = (tr & 1) * 4 + quad;
    bpt[nt] = Bs + R * 64 + ((c ^ (R & 7)) * 8);
  }

  f32x4 acc[2][NTW];
#pragma unroll
  for (int mi = 0; mi < 2; mi++)
#pragma unroll
    for (int nt = 0; nt < NTW; nt++) acc[mi][nt] = (f32x4){0.f, 0.f, 0.f, 0.f};

  // prologue: stage K-slab 0 into buffer 0
  gload16(agp, alds);
#pragma unroll
  for (int j = 0; j < BG; j++) gload16(bgp[j], blds[j]);
  __syncthreads();

  const int nk = K >> 5;
  int cur = 0;
  for (int tt = 0; tt < nk; ++tt) {
    if (tt + 1 < nk) {               // prefetch next slab; flies during compute
      const int nxt = cur ^ 1;
      const int koff = (tt + 1) * 32;
      gload16(agp + koff, alds + nxt * ASZ);
#pragma unroll
      for (int j = 0; j < BG; j++) gload16(bgp[j] + koff, blds[j] + nxt * BSZ);
    }
    const int ao = cur * ASZ, bo = cur * BSZ;
    bf16x8 af[2], bv[NTW];
#pragma unroll
    for (int mi = 0; mi < 2; mi++) af[mi] = *(const bf16x8*)(apt[mi] + ao);
#pragma unroll
    for (int nt = 0; nt < NTW; nt++) bv[nt] = *(const bf16x8*)(bpt[nt] + bo);
#pragma unroll
    for (int mi = 0; mi < 2; mi++)
#pragma unroll
      for (int nt = 0; nt < NTW; nt++)
        acc[mi][nt] = __builtin_amdgcn_mfma_f32_16x16x32_bf16(af[mi], bv[nt], acc[mi][nt], 0, 0, 0);
    if (tt + 1 < nk) __syncthreads(); // drains prefetch (post-compute)
    cur ^= 1;
  }

#pragma unroll
  for (int mi = 0; mi < 2; mi++) {
    int m_r0 = m0 + wr * 32 + mi * 16 + quad * 4;   // 4-aligned; 1000%4==0
#pragma unroll
    for (int nt = 0; nt < NTW; nt++) {
      int nbase = n0 + wc * (BN / 2) + nt * 16;     // wave-uniform region
      int n = nbase + mloc;
      if (vtg && nbase >= 1024 && nbase < 1536) {
        if (m_r0 < M) {                              // full 4-run valid (M%4==0)
          int bb = (m_r0 * 67109) >> 26;             // m/1000 for m<8000
          int ll = m_r0 - bb * 1000;
          int hh2 = (n - 1024) >> 6, dk = n & 63;
          float bn_ = bias[n];
          union { uint2 d; u16 s[4]; } pk;
#pragma unroll
          for (int r = 0; r < 4; r++) pk.s[r] = f2bf(acc[mi][nt][r] + bn_);
          u16* dst = vtg + ((size_t)(bb * 8 + hh2) * 64 + dk) * 1024 + ll;
          *(uint2*)dst = pk.d;                       // ll%4==0 -> 8B aligned
        }
      } else {
        float bn_ = bias[n];
#pragma unroll
        for (int r = 0; r < 4; r++) {
          int m = m_r0 + r;
          if (m >= M) continue;
          size_t crow = (size_t)m * N;
          float vsum = acc[mi][nt][r] + bn_;
          if (resid) vsum += bf2f(resid[crow + n]);
          if (n < nscale) vsum *= sval;
          if (relu) vsum = fmaxf(vsum, 0.f);
          C16[crow + n] = f2bf(vsum);
        }
      }
    }
  }
}

// ---------------- MFMA flash attention, R10: dbuf staging, Kp from global ---
// The clean staging experiment R5 confounded: keep R4's compute (Ps-LDS
// P-transpose, setprio), but stage K/V into DOUBLE-buffered LDS with ONE
// barrier per tile (prefetch for tile t+1 flies under tile t's compute —
// gemm-proven, no reg live-range). The LDS blocker (K/V dbuf +16KB) is
// removed by evicting Kp from LDS: kpf fragments read DIRECTLY from global.
// All 4 waves read the same 2KB/tile of kp rows -> L1-served; bytes are
// identical to the old Kp copy; oob rows (masked to -3e38) may read stray
// but mapped workspace. LDS = 16+16+5 = 37.9KB -> still 4 blocks/CU.
#define KT   64
#define PSLD 40    // per-wave P chunk row stride (16x32 tile)
__global__ __launch_bounds__(256)
void attn_mfma_kernel(const u16* __restrict__ qkv, const u16* __restrict__ vtg,
                      u16* __restrict__ ctx) {
  __shared__ u16 Ks[2 * KT * 64];      // 16KB dbuf [buf][key][dk], 8-chunk XOR
  __shared__ u16 Vt[2 * 64 * KT];      // 16KB dbuf [buf][dk][key], 8-chunk XOR
  __shared__ u16 Ps[4 * 16 * PSLD];    // 5KB per-wave P[16][32]

  // XCD swizzle: all 16 q-tiles of one (b,h) share linear%8 -> same XCD L2
  int Lid = blockIdx.x;                // 0..1023
  int qt = Lid >> 6;
  int bh = ((Lid & 7) << 3) | ((Lid >> 3) & 7);
  int b = bh >> 3, hh = bh & 7;
  int l0 = qt * 64;
  int t = threadIdx.x;
  int wv = t >> 6, lane = t & 63;
  int m = lane & 15, quad = lane >> 4;

  // Q (pre-scaled by 0.125*log2e) + fused qp (pre-scaled by 2*log2e)
  int lq = l0 + wv * 16 + m; if (lq > L_ - 1) lq = L_ - 1;
  const u16* qrow = qkv + (size_t)(b * L_ + lq) * QKVS + hh * DK_;
  bf16x8 qa0 = *(const bf16x8*)(qrow + quad * 8);
  bf16x8 qa1 = *(const bf16x8*)(qrow + 32 + quad * 8);
  bfrag qpa;
  if (quad < 2) {
    qpa.q = *(const uint4*)(qkv + (size_t)(b * L_ + lq) * QKVS + 1536 + hh * P_ + quad * 8);
  } else {
    qpa.q = make_uint4(0u, 0u, 0u, 0u);
  }

  // staging: slot s of row r holds chunk s^(r&7); 8 rows/wave/round, 2 rounds
  const u16* ks_g = qkv + ((size_t)b * L_ + (t >> 3)) * QKVS + 512 + hh * DK_
                    + ((t & 7) ^ ((t >> 3) & 7)) * 8;
  u16* ks_l = Ks + wv * 512;
  const u16* vt_g = vtg + ((size_t)bh * DK_ + (t >> 3)) * 1024
                    + ((t & 7) ^ ((t >> 3) & 7)) * 8;
  u16* vt_l = Vt + wv * 512;
  // kp fragment base (global; per-lane row added per tile)
  const u16* kp_g = qkv + (size_t)(b * L_) * QKVS + 1664 + hh * P_ + (quad & 1) * 8;

  f32x4 O[4];
#pragma unroll
  for (int nt = 0; nt < 4; nt++) O[nt] = (f32x4){0.f, 0.f, 0.f, 0.f};
  float lrun[4] = {0.f, 0.f, 0.f, 0.f};

  u16* pw = Ps + wv * (16 * PSLD);
  const u16* pr0 = pw + m * PSLD + quad * 8;
  const f32x4 zz = (f32x4){0.f, 0.f, 0.f, 0.f};

  // prologue: stage tile 0 into buffer 0
#pragma unroll
  for (int j = 0; j < 2; j++) {
    gload16(ks_g + (size_t)(j * 32) * QKVS, ks_l + j * 2048);
    gload16(vt_g + (size_t)j * 32 * 1024, vt_l + j * 2048);
  }
  __syncthreads();

  for (int tt = 0; tt < 16; ++tt) {
    const int s0 = tt * KT;
    const int c = tt & 1;
    if (tt < 15) {          // prefetch tile tt+1 into other buffer
      const int sn = s0 + KT, nb = c ^ 1;
#pragma unroll
      for (int j = 0; j < 2; j++) {
        gload16(ks_g + ((size_t)sn + j * 32) * QKVS, ks_l + nb * 4096 + j * 2048);
        gload16(vt_g + sn + (size_t)j * 32 * 1024, vt_l + nb * 4096 + j * 2048);
      }
    }
    // kp fragments for this tile (L1-hot; oob rows stray-but-mapped, masked)
    bfrag kpr[4];
#pragma unroll
    for (int nt = 0; nt < 4; nt++)
      kpr[nt].q = *(const uint4*)(kp_g + (size_t)(s0 + nt * 16 + m) * QKVS);

    const u16* Kc = Ks + c * 4096;
    const u16* Vc = Vt + c * 4096;

#pragma unroll
    for (int kc = 0; kc < 2; kc++) {
      float pv2[2][4];
#pragma unroll
      for (int h2 = 0; h2 < 2; h2++) {
        int nt = kc * 2 + h2;
        const u16* kb = Kc + (nt * 16 + m) * 64;
        int x0 = ((quad) ^ (m & 7)) * 8;
        int x1 = ((4 + quad) ^ (m & 7)) * 8;
        __builtin_amdgcn_s_setprio(1);
        f32x4 sacc = __builtin_amdgcn_mfma_f32_16x16x32_bf16(qa0, *(const bf16x8*)(kb + x0), zz, 0, 0, 0);
        sacc = __builtin_amdgcn_mfma_f32_16x16x32_bf16(qa1, *(const bf16x8*)(kb + x1), sacc, 0, 0, 0);
        f32x4 macc = __builtin_amdgcn_mfma_f32_16x16x32_bf16(qpa.b, kpr[nt].b, zz, 0, 0, 0);
        __builtin_amdgcn_s_setprio(0);
        bool oob = (s0 + nt * 16 + m) >= L_;
#pragma unroll
        for (int r = 0; r < 4; r++) {
          float e = fexp2(macc[r]);                 // macc = 2*log2e*x
          float d = frcp(e + 1.f);
          float th = fmaf(d, -2.f * L2E_, L2E_);    // log2e*tanh(x)
          float s = sacc[r] + th;
          if (oob) s = -3e38f;
          float p = fexp2(s - SHFT_);
          pv2[h2][r] = p;
          lrun[r] += p;
        }
      }
      // P chunk: C-layout -> per-wave 16x32 LDS -> A-layout (same wave)
#pragma unroll
      for (int h2 = 0; h2 < 2; h2++)
#pragma unroll
        for (int r = 0; r < 4; r++)
          pw[(quad * 4 + r) * PSLD + h2 * 16 + m] = f2bf(pv2[h2][r]);
      bf16x8 pa = *(const bf16x8*)pr0;
      __builtin_amdgcn_s_setprio(1);
#pragma unroll
      for (int ntd = 0; ntd < 4; ntd++) {
        const u16* vb = Vc + (ntd * 16 + m) * KT + (((kc * 4 + quad) ^ (m & 7)) * 8);
        O[ntd] = __builtin_amdgcn_mfma_f32_16x16x32_bf16(pa, *(const bf16x8*)vb, O[ntd], 0, 0, 0);
      }
      __builtin_amdgcn_s_setprio(0);
    }
    if (tt < 15) __syncthreads();   // drains prefetch (post-compute)
  }

  float inv[4];
#pragma unroll
  for (int r = 0; r < 4; r++) {
#pragma unroll
    for (int msk = 1; msk < 16; msk <<= 1) lrun[r] += __shfl_xor(lrun[r], msk, 64);
    inv[r] = frcp(lrun[r]);
  }
#pragma unroll
  for (int r = 0; r < 4; r++) {
    int l = l0 + wv * 16 + quad * 4 + r;
    if (l >= L_) continue;
    u16* crow = ctx + ((size_t)(b * L_ + l)) * DM_ + hh * DK_;
#pragma unroll
    for (int nt = 0; nt < 4; nt++) crow[nt * 16 + m] = f2bf(O[nt][r] * inv[r]);
  }
}

// ---------------- layernorm, R9: one WAVE per row (no LDS, no barriers) -----
__global__ __launch_bounds__(256)
void ln_kernel(const u16* __restrict__ a, const float* __restrict__ g,
               const float* __restrict__ be, u16* __restrict__ o) {
  int wv = threadIdx.x >> 6, lane = threadIdx.x & 63;
  int row = blockIdx.x * 4 + wv;
  size_t base = (size_t)row * DM_ + lane * 8;
  bfrag v; v.q = *(const uint4*)(a + base);
  float x[8], s = 0.f, ss = 0.f;
#pragma unroll
  for (int i = 0; i < 8; i++) { x[i] = bf2f(v.u[i]); s += x[i]; ss = fmaf(x[i], x[i], ss); }
#pragma unroll
  for (int off = 32; off >= 1; off >>= 1) { s += __shfl_xor(s, off, 64); ss += __shfl_xor(ss, off, 64); }
  float mean = s * (1.0f / DM_);
  float var = ss * (1.0f / DM_) - mean * mean;
  float rstd = rsqrtf(var + EPS_);
  float4 g0 = *(const float4*)(g + lane * 8), g1 = *(const float4*)(g + lane * 8 + 4);
  float4 b0 = *(const float4*)(be + lane * 8), b1 = *(const float4*)(be + lane * 8 + 4);
  float gv[8] = {g0.x, g0.y, g0.z, g0.w, g1.x, g1.y, g1.z, g1.w};
  float bv[8] = {b0.x, b0.y, b0.z, b0.w, b1.x, b1.y, b1.z, b1.w};
  bfrag r;
#pragma unroll
  for (int i = 0; i < 8; i++) r.u[i] = f2bf((x[i] - mean) * rstd * gv[i] + bv[i]);
  *(uint4*)(o + base) = r.q;
}

// ---------------- fused double layernorm, R9 wave-per-row -------------------
__global__ __launch_bounds__(256)
void ln2x_kernel(const u16* __restrict__ hin, const u16* __restrict__ y,
                 const float* __restrict__ g, const float* __restrict__ be,
                 u16* __restrict__ o16) {
  int wv = threadIdx.x >> 6, lane = threadIdx.x & 63;
  int row = blockIdx.x * 4 + wv;
  size_t base = (size_t)row * DM_ + lane * 8;
  bfrag hv; hv.q = *(const uint4*)(hin + base);
  bfrag yv; yv.q = *(const uint4*)(y + base);
  float4 g0 = *(const float4*)(g + lane * 8), g1 = *(const float4*)(g + lane * 8 + 4);
  float4 b0 = *(const float4*)(be + lane * 8), b1 = *(const float4*)(be + lane * 8 + 4);
  float gv[8] = {g0.x, g0.y, g0.z, g0.w, g1.x, g1.y, g1.z, g1.w};
  float bv[8] = {b0.x, b0.y, b0.z, b0.w, b1.x, b1.y, b1.z, b1.w};
  float x[8], yy[8], s = 0.f, ss = 0.f;
#pragma unroll
  for (int i = 0; i < 8; i++) {
    yy[i] = bf2f(yv.u[i]);
    x[i] = bf2f(hv.u[i]) + yy[i];
    s += x[i]; ss = fmaf(x[i], x[i], ss);
  }
#pragma unroll
  for (int off = 32; off >= 1; off >>= 1) { s += __shfl_xor(s, off, 64); ss += __shfl_xor(ss, off, 64); }
  float mean = s * (1.0f / DM_);
  float var = ss * (1.0f / DM_) - mean * mean;
  float rstd = rsqrtf(var + EPS_);
  float h2[8]; s = 0.f; ss = 0.f;
#pragma unroll
  for (int i = 0; i < 8; i++) {
    h2[i] = (x[i] - mean) * rstd * gv[i] + bv[i] + yy[i];
    s += h2[i]; ss = fmaf(h2[i], h2[i], ss);
  }
#pragma unroll
  for (int off = 32; off >= 1; off >>= 1) { s += __shfl_xor(s, off, 64); ss += __shfl_xor(ss, off, 64); }
  mean = s * (1.0f / DM_);
  var = ss * (1.0f / DM_) - mean * mean;
  rstd = rsqrtf(var + EPS_);
  bfrag r;
#pragma unroll
  for (int i = 0; i < 8; i++) r.u[i] = f2bf((h2[i] - mean) * rstd * gv[i] + bv[i]);
  *(uint4*)(o16 + base) = r.q;
}

// ---------------- final head (bf16 in) --------------------------------------
__global__ __launch_bounds__(512)
void final_kernel(const u16* __restrict__ h, const float* __restrict__ gn,
                  const float* __restrict__ bn, const float* __restrict__ fcw,
                  const float* __restrict__ fcb, float* __restrict__ out) {
  int b = blockIdx.x;
  int t = threadIdx.x;
  size_t base = ((size_t)b * L_ + (L_ - 1)) * DM_;
  float x = bf2f(h[base + t]);
  float s = wave_reduce_sum(x);
  float ss = wave_reduce_sum(x * x);
  __shared__ float sh_s[8], sh_ss[8];
  int wv = t >> 6, lane = t & 63;
  if (lane == 0) { sh_s[wv] = s; sh_ss[wv] = ss; }
  __syncthreads();
  float S = 0.f, SS = 0.f;
#pragma unroll
  for (int i = 0; i < 8; i++) { S += sh_s[i]; SS += sh_ss[i]; }
  float mean = S * (1.0f / DM_);
  float var = SS * (1.0f / DM_) - mean * mean;
  float rstd = rsqrtf(var + EPS_);
  __shared__ float hn[DM_];
  hn[t] = (x - mean) * rstd * gn[t] + bn[t];
  __syncthreads();
  if (t < PRED_) {
    float acc = fcb[t];
#pragma unroll 8
    for (int d = 0; d < DM_; d++) acc = fmaf(hn[d], fcw[d * PRED_ + t], acc);
    out[b * PRED_ + t] = acc;
  }
}

// ---------------- driver ----------------
extern "C" void kernel_launch(void* const* d_in, const int* in_sizes, int n_in,
                              void* d_out, int out_size, void* d_ws, size_t ws_size,
                              hipStream_t stream) {
  const float* x     = (const float*)d_in[0];
  const float* emb_w = (const float*)d_in[1];
  const float* emb_b = (const float*)d_in[2];
  const float* pe    = (const float*)d_in[3];
  const float* Wq = (const float*)d_in[4];  const float* bq = (const float*)d_in[5];
  const float* Wk = (const float*)d_in[6];  const float* bk = (const float*)d_in[7];
  const float* Wv = (const float*)d_in[8];  const float* bv = (const float*)d_in[9];
  const float* Wo = (const float*)d_in[10]; const float* bo = (const float*)d_in[11];
  const float* W1 = (const float*)d_in[12]; const float* b1 = (const float*)d_in[13];
  const float* W2 = (const float*)d_in[14]; const float* b2 = (const float*)d_in[15];
  const float* g1 = (const float*)d_in[16]; const float* be1 = (const float*)d_in[17];
  const float* g2 = (const float*)d_in[18]; const float* be2 = (const float*)d_in[19];
  const float* lm_qw = (const float*)d_in[20]; const float* lm_qb = (const float*)d_in[21];
  const float* lm_kw = (const float*)d_in[22]; const float* lm_kb = (const float*)d_in[23];
  const float* gn = (const float*)d_in[24]; const float* bn = (const float*)d_in[25];
  const float* fc_w = (const float*)d_in[26]; const float* fc_b = (const float*)d_in[27];
  float* out = (float*)d_out;

  const size_t ROWS = (size_t)B_ * L_;     // 8000
  u16* qkv16 = (u16*)d_ws;                               // [8000][1792]
  u16* ctx16 = qkv16 + ROWS * QKVS;                      // [8000][512]
  u16* ffn1  = qkv16;                                    // [8000][2048] alias (qkv+ctx)
  u16* h16   = ctx16 + ROWS * DM_;                       // [8000][512]
  u16* t16   = h16 + ROWS * DM_;                         // [8000][512]
  u16* vtg   = t16 + ROWS * DM_;                         // [64][64][1024] dedicated
                                                         // (tail keys keep 0xAA poison =
                                                         //  finite bf16; P=0 -> safe)
  u16* Wqkv_t = vtg + (size_t)64 * 64 * 1024;            // [NL][1792][512]
  u16* Wo_t   = Wqkv_t + (size_t)NL_ * QKVS * DM_;       // [NL][512][512]
  u16* W1_t   = Wo_t + (size_t)NL_ * DM_ * DM_;          // [NL][2048][512]
  u16* W2_t   = W1_t + (size_t)NL_ * DFF_ * DM_;         // [NL][512][2048]
  float* bqkv = (float*)(W2_t + (size_t)NL_ * DM_ * DFF_);

  transpose_w<<<dim3(16, 16, NL_), 256, 0, stream>>>(Wq, Wqkv_t, DM_, DM_, (size_t)DM_ * DM_, (size_t)QKVS * DM_, 0, DM_);
  transpose_w<<<dim3(16, 16, NL_), 256, 0, stream>>>(Wk, Wqkv_t, DM_, DM_, (size_t)DM_ * DM_, (size_t)QKVS * DM_, 512, DM_);
  transpose_w<<<dim3(16, 16, NL_), 256, 0, stream>>>(Wv, Wqkv_t, DM_, DM_, (size_t)DM_ * DM_, (size_t)QKVS * DM_, 1024, DM_);
  transpose_w<<<dim3(16, 16, NL_), 256, 0, stream>>>(Wo, Wo_t, DM_, DM_, (size_t)DM_ * DM_, (size_t)DM_ * DM_, 0, DM_);
  transpose_w<<<dim3(64, 16, NL_), 256, 0, stream>>>(W1, W1_t, DM_, DFF_, (size_t)DM_ * DFF_, (size_t)DFF_ * DM_, 0, DM_);
  transpose_w<<<dim3(16, 64, NL_), 256, 0, stream>>>(W2, W2_t, DFF_, DM_, (size_t)DFF_ * DM_, (size_t)DM_ * DFF_, 0, DFF_);
  wfuse_kernel<<<dim3(H_, 2, NL_), 256, 0, stream>>>(Wq, Wk, lm_qw, lm_kw, Wqkv_t);
  concat_bias<<<NL_ * QKVS / 256, 256, 0, stream>>>(bq, bk, bv, lm_qw, lm_qb, lm_kw, lm_kb, bqkv);

  embed_kernel<<<dim3((unsigned)ROWS), 512, 0, stream>>>(x, emb_w, emb_b, pe, h16);

  dim3 g_qkv(QKVS / 128, 125);   // (14, 125)
  dim3 g_ffn1(DFF_ / 128, 125);  // (16, 125)
  dim3 g_n512(DM_ / 64, 125);    // (8, 125)
  dim3 g_attn(1024);
  dim3 g_ln(2000);               // 4 rows/block, wave-per-row

  for (int i = 0; i < NL_; i++) {
    gemm64<128><<<g_qkv, 256, 0, stream>>>(h16, Wqkv_t + (size_t)i * QKVS * DM_,
        bqkv + i * QKVS, nullptr, qkv16, vtg, 8000, DM_, QKVS, 0, 512, C_QS);

    attn_mfma_kernel<<<g_attn, 256, 0, stream>>>(qkv16, vtg, ctx16);

    gemm64<64><<<g_n512, 256, 0, stream>>>(ctx16, Wo_t + (size_t)i * DM_ * DM_,
        bo + i * DM_, h16, t16, nullptr, 8000, DM_, DM_, 0, 0, 1.0f);
    ln_kernel<<<g_ln, 256, 0, stream>>>(t16, g1 + i * DM_, be1 + i * DM_, h16);

    gemm64<128><<<g_ffn1, 256, 0, stream>>>(h16, W1_t + (size_t)i * DFF_ * DM_,
        b1 + i * DFF_, nullptr, ffn1, nullptr, 8000, DM_, DFF_, 1, 0, 1.0f);
    gemm64<64><<<g_n512, 256, 0, stream>>>(ffn1, W2_t + (size_t)i * DM_ * DFF_,
        b2 + i * DM_, nullptr, t16, nullptr, 8000, DFF_, DM_, 0, 0, 1.0f);

    ln2x_kernel<<<g_ln, 256, 0, stream>>>(h16, t16, g2 + i * DM_, be2 + i * DM_, h16);
  }

  final_kernel<<<B_, 512, 0, stream>>>(h16, gn, bn, fc_w, fc_b, out);
}

// Round 11
// 1033.859 us; speedup vs baseline: 1.0082x; 1.0082x over previous
//
#include <hip/hip_runtime.h>
#include <math.h>

// Problem constants (PCUTransformer)
#define B_    8
#define L_    1000
#define F_    7
#define DM_   512
#define H_    8
#define DFF_  2048
#define NL_   4
#define PRED_ 50
#define DK_   64
#define P_    16
#define EPS_  1e-5f
#define QKVS  1792      // fused row: q(512) k(512) v-gap(512) qp(128) kp(128)

#define L2E_   1.4426950408889634f
#define C_QS   0.18033688011112042f   // 0.125 * log2(e) folded into q
#define BS_QP  2.8853900817779268f    // 2*log2(e) folded into fused qp weights
#define SHFT_  24.0f                  // fixed softmax shift (cancels in normalize)

typedef unsigned short u16;
typedef __bf16 bf16x8 __attribute__((ext_vector_type(8)));
typedef float  f32x4  __attribute__((ext_vector_type(4)));

// ---------------- helpers ----------------
__device__ inline float wave_reduce_sum(float x) {
#pragma unroll
  for (int off = 32; off >= 1; off >>= 1) x += __shfl_xor(x, off, 64);
  return x;
}
__device__ inline u16 f2bf(float f) {   // RNE float->bf16 bits
  unsigned int u = __float_as_uint(f);
  unsigned int r = u + 0x7FFFu + ((u >> 16) & 1u);
  return (u16)(r >> 16);
}
__device__ inline unsigned int pack2(float a, float b) {
  return (unsigned int)f2bf(a) | ((unsigned int)f2bf(b) << 16);
}
__device__ inline float bf2f(u16 u) { return __uint_as_float(((unsigned int)u) << 16); }
__device__ inline float fexp2(float x) { return __builtin_amdgcn_exp2f(x); }
__device__ inline float frcp(float x) { return __builtin_amdgcn_rcpf(x); }

union bfrag { bf16x8 b; uint4 q; u16 u[8]; };

// async global->LDS, 16B per lane; lds base wave-uniform, HW scatters lane*16
__device__ inline void gload16(const u16* g, u16* l) {
  __builtin_amdgcn_global_load_lds(
      (const __attribute__((address_space(1))) void*)g,
      (__attribute__((address_space(3))) void*)l, 16, 0, 0);
}

// ---------------- weight transpose-convert: out[n][k] = bf16(in[k][n]) ------
__global__ __launch_bounds__(256)
void transpose_w(const float* __restrict__ in, u16* __restrict__ out,
                 int K, int N, size_t in_lstride, size_t out_lstride,
                 int row_off, int out_ld) {
  __shared__ float tile[32][33];
  int z = blockIdx.z;
  int kk0 = blockIdx.y * 32, nn0 = blockIdx.x * 32;
  int tx = threadIdx.x & 31, ty = threadIdx.x >> 5;
  const float* ip = in + z * in_lstride;
  u16* op = out + z * out_lstride;
#pragma unroll
  for (int i = 0; i < 4; i++)
    tile[ty + i * 8][tx] = ip[(size_t)(kk0 + ty + i * 8) * N + nn0 + tx];
  __syncthreads();
#pragma unroll
  for (int i = 0; i < 4; i++)
    op[(size_t)(row_off + nn0 + ty + i * 8) * out_ld + kk0 + tx] = f2bf(tile[tx][ty + i * 8]);
}

// ---------------- fused lm weights: Wt rows 1536+side*128+hh*16+p -----------
__global__ __launch_bounds__(256)
void wfuse_kernel(const float* __restrict__ Wq, const float* __restrict__ Wk,
                  const float* __restrict__ lmqw, const float* __restrict__ lmkw,
                  u16* __restrict__ Wt) {
  int hh = blockIdx.x, side = blockIdx.y, layer = blockIdx.z;
  const float* W = (side ? Wk : Wq) + (size_t)layer * 512 * 512;
  const float* lw = side ? lmkw : lmqw;
  float scale = side ? 1.0f : BS_QP;
  __shared__ float lws[64][17];
  int t = threadIdx.x;
  for (int i = t; i < 1024; i += 256) lws[i >> 4][i & 15] = lw[i];
  __syncthreads();
  int p = t & 15, kk = t >> 4;
  u16* orow = Wt + (size_t)layer * QKVS * 512 + (size_t)(1536 + side * 128 + hh * 16 + p) * 512;
  for (int kb = 0; kb < 32; kb++) {
    int k = kb * 16 + kk;
    const float* wr = W + (size_t)k * 512 + hh * 64;
    float acc = 0.f;
#pragma unroll
    for (int d = 0; d < 64; d++) acc = fmaf(wr[d], lws[d][p], acc);
    orow[k] = f2bf(acc * scale);
  }
}

// ---------------- bias assembly: [NL][1792] ---------------------------------
__global__ __launch_bounds__(256)
void concat_bias(const float* __restrict__ bq, const float* __restrict__ bk,
                 const float* __restrict__ bv,
                 const float* __restrict__ lmqw, const float* __restrict__ lmqb,
                 const float* __restrict__ lmkw, const float* __restrict__ lmkb,
                 float* __restrict__ bqkv) {
  int i = blockIdx.x * 256 + threadIdx.x;   // NL*1792
  int l = i / QKVS, j = i % QKVS;
  float v;
  if (j < 512) v = bq[l * 512 + j];
  else if (j < 1024) v = bk[l * 512 + j - 512];
  else if (j < 1536) v = bv[l * 512 + j - 1024];
  else if (j < 1664) {
    int hh = (j - 1536) >> 4, p = (j - 1536) & 15;
    float acc = lmqb[p];
#pragma unroll
    for (int d = 0; d < 64; d++) acc = fmaf(bq[l * 512 + hh * 64 + d], lmqw[d * 16 + p], acc);
    v = acc * BS_QP;
  } else {
    int hh = (j - 1664) >> 4, p = (j - 1664) & 15;
    float acc = lmkb[p];
#pragma unroll
    for (int d = 0; d < 64; d++) acc = fmaf(bk[l * 512 + hh * 64 + d], lmkw[d * 16 + p], acc);
    v = acc;
  }
  bqkv[i] = v;
}

// ---------------- embedding (bf16 out) --------------------------------------
__global__ __launch_bounds__(512)
void embed_kernel(const float* __restrict__ x, const float* __restrict__ emb_w,
                  const float* __restrict__ emb_b, const float* __restrict__ pe,
                  u16* __restrict__ h16) {
  int bl = blockIdx.x;
  int l = bl % L_;
  int d = threadIdx.x;
  const float* xr = x + (size_t)bl * F_;
  float acc = emb_b[d] + pe[(size_t)l * DM_ + d];
#pragma unroll
  for (int f = 0; f < F_; f++) acc = fmaf(xr[f], emb_w[f * DM_ + d], acc);
  h16[(size_t)bl * DM_ + d] = f2bf(acc);
}

// ---------------- bf16 MFMA GEMM, BM=64, BK=32, LDS dbuf --------------------
// R11: continue the verified occupancy lever (R9: 2->6 blocks/CU = -85us).
// BN=64 drops the dbuf to 16KB -> 8 blocks/CU (the 32-wave cap, full CU).
// B L2-traffic unchanged; A-traffic doubles (+~3us, L2 BW is cheap); per-slab
// MFMA halves — affordable iff TLP is the binding constraint (the test).
template<int BN>
__global__ __launch_bounds__(256)
void gemm64(const u16* __restrict__ A, const u16* __restrict__ Bt,
            const float* __restrict__ bias, const u16* __restrict__ resid,
            u16* __restrict__ C16, u16* __restrict__ vtg,
            int M, int K, int N, int relu, int nscale, float sval) {
  constexpr int NTW = BN / 32;
  constexpr int BG  = BN / 64;          // B gloads per wave (128->2, 64->1)
  constexpr int ASZ = 32 * 64;          // 32 lines of 128B = 4KB per buffer
  constexpr int BSZ = (BN / 2) * 64;
  __shared__ u16 As[2 * ASZ];
  __shared__ u16 Bs[2 * BSZ];
  int t = threadIdx.x;
  int w = t >> 6, lane = t & 63;
  int wr = w >> 1, wc = w & 1;
  int mloc = lane & 15, quad = lane >> 4;
  int m0 = blockIdx.y * 64, n0 = blockIdx.x * BN;

  // staging: line R slot s holds chunk c=s^(R&7) -> global row 2R+(c>>2),
  // k-cols (c&3)*8..+8. Global addr carries the swizzle; LDS dest linear.
  const u16* agp; u16* alds;
  {
    int R = w * 8 + (lane >> 3);               // A line 0..31
    int c = (lane & 7) ^ (R & 7);
    int gm = m0 + 2 * R + (c >> 2); if (gm > M - 1) gm = M - 1;
    agp = A + (size_t)gm * K + (c & 3) * 8;
    alds = As + (w * 8) * 64;
  }
  const u16* bgp[BG]; u16* blds[BG];
#pragma unroll
  for (int j = 0; j < BG; j++) {
    int R = w * (8 * BG) + j * 8 + (lane >> 3); // B line 0..BN/2-1
    int c = (lane & 7) ^ (R & 7);
    bgp[j] = Bt + (size_t)(n0 + 2 * R + (c >> 2)) * K + (c & 3) * 8;
    blds[j] = Bs + (w * (8 * BG) + j * 8) * 64;
  }
  // fragment read: row tr, k-chunk quad -> line tr>>1, chunk (tr&1)*4+quad
  const u16* apt[2];
#pragma unroll
  for (int mi = 0; mi < 2; mi++) {
    int tr = wr * 32 + mi * 16 + mloc;
    int R = tr >> 1, c = (tr & 1) * 4 + quad;
    apt[mi] = As + R * 64 + ((c ^ (R & 7)) * 8);
  }
  const u16* bpt[NTW];
#pragma unroll
  for (int nt = 0; nt < NTW; nt++) {
    int tr = wc * (BN / 2) + nt * 16 + mloc;
    int R = tr >> 1, c = (tr & 1) * 4 + quad;
    bpt[nt] = Bs + R * 64 + ((c ^ (R & 7)) * 8);
  }

  f32x4 acc[2][NTW];
#pragma unroll
  for (int mi = 0; mi < 2; mi++)
#pragma unroll
    for (int nt = 0; nt < NTW; nt++) acc[mi][nt] = (f32x4){0.f, 0.f, 0.f, 0.f};

  // prologue: stage K-slab 0 into buffer 0
  gload16(agp, alds);
#pragma unroll
  for (int j = 0; j < BG; j++) gload16(bgp[j], blds[j]);
  __syncthreads();

  const int nk = K >> 5;
  int cur = 0;
  for (int tt = 0; tt < nk; ++tt) {
    if (tt + 1 < nk) {               // prefetch next slab; flies during compute
      const int nxt = cur ^ 1;
      const int koff = (tt + 1) * 32;
      gload16(agp + koff, alds + nxt * ASZ);
#pragma unroll
      for (int j = 0; j < BG; j++) gload16(bgp[j] + koff, blds[j] + nxt * BSZ);
    }
    const int ao = cur * ASZ, bo = cur * BSZ;
    bf16x8 af[2], bv[NTW];
#pragma unroll
    for (int mi = 0; mi < 2; mi++) af[mi] = *(const bf16x8*)(apt[mi] + ao);
#pragma unroll
    for (int nt = 0; nt < NTW; nt++) bv[nt] = *(const bf16x8*)(bpt[nt] + bo);
#pragma unroll
    for (int mi = 0; mi < 2; mi++)
#pragma unroll
      for (int nt = 0; nt < NTW; nt++)
        acc[mi][nt] = __builtin_amdgcn_mfma_f32_16x16x32_bf16(af[mi], bv[nt], acc[mi][nt], 0, 0, 0);
    if (tt + 1 < nk) __syncthreads(); // drains prefetch (post-compute)
    cur ^= 1;
  }

#pragma unroll
  for (int mi = 0; mi < 2; mi++) {
    int m_r0 = m0 + wr * 32 + mi * 16 + quad * 4;   // 4-aligned; 1000%4==0
#pragma unroll
    for (int nt = 0; nt < NTW; nt++) {
      int nbase = n0 + wc * (BN / 2) + nt * 16;     // wave-uniform region
      int n = nbase + mloc;
      if (vtg && nbase >= 1024 && nbase < 1536) {
        if (m_r0 < M) {                              // full 4-run valid (M%4==0)
          int bb = (m_r0 * 67109) >> 26;             // m/1000 for m<8000
          int ll = m_r0 - bb * 1000;
          int hh2 = (n - 1024) >> 6, dk = n & 63;
          float bn_ = bias[n];
          union { uint2 d; u16 s[4]; } pk;
#pragma unroll
          for (int r = 0; r < 4; r++) pk.s[r] = f2bf(acc[mi][nt][r] + bn_);
          u16* dst = vtg + ((size_t)(bb * 8 + hh2) * 64 + dk) * 1024 + ll;
          *(uint2*)dst = pk.d;                       // ll%4==0 -> 8B aligned
        }
      } else {
        float bn_ = bias[n];
#pragma unroll
        for (int r = 0; r < 4; r++) {
          int m = m_r0 + r;
          if (m >= M) continue;
          size_t crow = (size_t)m * N;
          float vsum = acc[mi][nt][r] + bn_;
          if (resid) vsum += bf2f(resid[crow + n]);
          if (n < nscale) vsum *= sval;
          if (relu) vsum = fmaxf(vsum, 0.f);
          C16[crow + n] = f2bf(vsum);
        }
      }
    }
  }
}

// ---------------- MFMA flash attention (R4 version: PARKED at best) ---------
// Three structures measured: R4 2-barrier+Ps-LDS = 56.2-57.1; R5 in-reg-shfl
// = 58.6; R10 dbuf+Kp-from-global = 63.0 (scattered kp global loads on the
// mask-MFMA critical path beat the LDS broadcast they replaced). R4 wins;
// floor is the softmax trans-op chain. Reverted to R4, parked permanently.
#define KT   64
#define KPLD 24    // Kp row stride (48B)
#define PSLD 40    // per-wave P chunk row stride (16x32 tile)
__global__ __launch_bounds__(256)
void attn_mfma_kernel(const u16* __restrict__ qkv, const u16* __restrict__ vtg,
                      u16* __restrict__ ctx) {
  __shared__ u16 Ks[KT * 64];          // 8192B [key][dk], 8-chunk XOR
  __shared__ u16 Vt[64 * KT];          // 8192B [dk][key], 8-chunk XOR
  __shared__ u16 Kp[KT * KPLD];        // 3072B [key][p 0..15]
  __shared__ u16 Ps[4 * 16 * PSLD];    // 5120B per-wave P[16][32]

  // XCD swizzle: all 16 q-tiles of one (b,h) share linear%8 -> same XCD L2
  int Lid = blockIdx.x;                // 0..1023
  int qt = Lid >> 6;
  int bh = ((Lid & 7) << 3) | ((Lid >> 3) & 7);
  int b = bh >> 3, hh = bh & 7;
  int l0 = qt * 64;
  int t = threadIdx.x;
  int wv = t >> 6, lane = t & 63;
  int m = lane & 15, quad = lane >> 4;

  // Q (pre-scaled by 0.125*log2e) + fused qp (pre-scaled by 2*log2e)
  int lq = l0 + wv * 16 + m; if (lq > L_ - 1) lq = L_ - 1;
  const u16* qrow = qkv + (size_t)(b * L_ + lq) * QKVS + hh * DK_;
  bf16x8 qa0 = *(const bf16x8*)(qrow + quad * 8);
  bf16x8 qa1 = *(const bf16x8*)(qrow + 32 + quad * 8);
  bfrag qpa;
  if (quad < 2) {
    qpa.q = *(const uint4*)(qkv + (size_t)(b * L_ + lq) * QKVS + 1536 + hh * P_ + quad * 8);
  } else {
    qpa.q = make_uint4(0u, 0u, 0u, 0u);
  }

  // staging: slot s of row r holds chunk s^(r&7); 8 rows/wave/round, 2 rounds
  const u16* ks_g = qkv + ((size_t)b * L_ + (t >> 3)) * QKVS + 512 + hh * DK_
                    + ((t & 7) ^ ((t >> 3) & 7)) * 8;
  u16* ks_l = Ks + (t >> 6) * 512;
  const u16* vt_g = vtg + ((size_t)bh * DK_ + (t >> 3)) * 1024
                    + ((t & 7) ^ ((t >> 3) & 7)) * 8;
  u16* vt_l = Vt + (t >> 6) * 512;

  f32x4 O[4];
#pragma unroll
  for (int nt = 0; nt < 4; nt++) O[nt] = (f32x4){0.f, 0.f, 0.f, 0.f};
  float lrun[4] = {0.f, 0.f, 0.f, 0.f};

  u16* pw = Ps + wv * (16 * PSLD);
  const u16* pr0 = pw + m * PSLD + quad * 8;
  const f32x4 zz = (f32x4){0.f, 0.f, 0.f, 0.f};

  for (int s0 = 0; s0 < L_; s0 += KT) {
    uint4 p0, p1;
    if (t < KT) {
      int sg2 = s0 + t; if (sg2 > L_ - 1) sg2 = L_ - 1;
      const u16* pr = qkv + (size_t)(b * L_ + sg2) * QKVS + 1664 + hh * P_;
      p0 = *(const uint4*)(pr);
      p1 = *(const uint4*)(pr + 8);
    }
    __syncthreads();   // B1: prev-tile Ks/Vt/Kp reads done
#pragma unroll
    for (int j = 0; j < 2; j++) {
      gload16(ks_g + ((size_t)s0 + j * 32) * QKVS, ks_l + j * 2048);
      gload16(vt_g + s0 + (size_t)j * 32 * 1024, vt_l + j * 2048);
    }
    if (t < KT) {
      *(uint4*)&Kp[t * KPLD]     = p0;
      *(uint4*)&Kp[t * KPLD + 8] = p1;
    }
    __syncthreads();   // B2: tile staged

#pragma unroll
    for (int kc = 0; kc < 2; kc++) {
      float pv2[2][4];
#pragma unroll
      for (int h2 = 0; h2 < 2; h2++) {
        int nt = kc * 2 + h2;
        const u16* kb = Ks + (nt * 16 + m) * 64;
        int x0 = ((quad) ^ (m & 7)) * 8;
        int x1 = ((4 + quad) ^ (m & 7)) * 8;
        __builtin_amdgcn_s_setprio(1);
        f32x4 sacc = __builtin_amdgcn_mfma_f32_16x16x32_bf16(qa0, *(const bf16x8*)(kb + x0), zz, 0, 0, 0);
        sacc = __builtin_amdgcn_mfma_f32_16x16x32_bf16(qa1, *(const bf16x8*)(kb + x1), sacc, 0, 0, 0);
        bf16x8 kpf = *(const bf16x8*)(Kp + (nt * 16 + m) * KPLD + (quad & 1) * 8);
        f32x4 macc = __builtin_amdgcn_mfma_f32_16x16x32_bf16(qpa.b, kpf, zz, 0, 0, 0);
        __builtin_amdgcn_s_setprio(0);
        bool oob = (s0 + nt * 16 + m) >= L_;
#pragma unroll
        for (int r = 0; r < 4; r++) {
          float e = fexp2(macc[r]);                 // macc = 2*log2e*x
          float d = frcp(e + 1.f);
          float th = fmaf(d, -2.f * L2E_, L2E_);    // log2e*tanh(x)
          float s = sacc[r] + th;
          if (oob) s = -3e38f;
          float p = fexp2(s - SHFT_);
          pv2[h2][r] = p;
          lrun[r] += p;
        }
      }
      // P chunk: C-layout -> per-wave 16x32 LDS -> A-layout (same wave)
#pragma unroll
      for (int h2 = 0; h2 < 2; h2++)
#pragma unroll
        for (int r = 0; r < 4; r++)
          pw[(quad * 4 + r) * PSLD + h2 * 16 + m] = f2bf(pv2[h2][r]);
      bf16x8 pa = *(const bf16x8*)pr0;
      __builtin_amdgcn_s_setprio(1);
#pragma unroll
      for (int ntd = 0; ntd < 4; ntd++) {
        const u16* vb = Vt + (ntd * 16 + m) * KT + (((kc * 4 + quad) ^ (m & 7)) * 8);
        O[ntd] = __builtin_amdgcn_mfma_f32_16x16x32_bf16(pa, *(const bf16x8*)vb, O[ntd], 0, 0, 0);
      }
      __builtin_amdgcn_s_setprio(0);
    }
  }

  float inv[4];
#pragma unroll
  for (int r = 0; r < 4; r++) {
#pragma unroll
    for (int msk = 1; msk < 16; msk <<= 1) lrun[r] += __shfl_xor(lrun[r], msk, 64);
    inv[r] = frcp(lrun[r]);
  }
#pragma unroll
  for (int r = 0; r < 4; r++) {
    int l = l0 + wv * 16 + quad * 4 + r;
    if (l >= L_) continue;
    u16* crow = ctx + ((size_t)(b * L_ + l)) * DM_ + hh * DK_;
#pragma unroll
    for (int nt = 0; nt < 4; nt++) crow[nt * 16 + m] = f2bf(O[nt][r] * inv[r]);
  }
}

// ---------------- layernorm, one WAVE per row (no LDS, no barriers) ---------
__global__ __launch_bounds__(256)
void ln_kernel(const u16* __restrict__ a, const float* __restrict__ g,
               const float* __restrict__ be, u16* __restrict__ o) {
  int wv = threadIdx.x >> 6, lane = threadIdx.x & 63;
  int row = blockIdx.x * 4 + wv;
  size_t base = (size_t)row * DM_ + lane * 8;
  bfrag v; v.q = *(const uint4*)(a + base);
  float x[8], s = 0.f, ss = 0.f;
#pragma unroll
  for (int i = 0; i < 8; i++) { x[i] = bf2f(v.u[i]); s += x[i]; ss = fmaf(x[i], x[i], ss); }
#pragma unroll
  for (int off = 32; off >= 1; off >>= 1) { s += __shfl_xor(s, off, 64); ss += __shfl_xor(ss, off, 64); }
  float mean = s * (1.0f / DM_);
  float var = ss * (1.0f / DM_) - mean * mean;
  float rstd = rsqrtf(var + EPS_);
  float4 g0 = *(const float4*)(g + lane * 8), g1 = *(const float4*)(g + lane * 8 + 4);
  float4 b0 = *(const float4*)(be + lane * 8), b1 = *(const float4*)(be + lane * 8 + 4);
  float gv[8] = {g0.x, g0.y, g0.z, g0.w, g1.x, g1.y, g1.z, g1.w};
  float bv[8] = {b0.x, b0.y, b0.z, b0.w, b1.x, b1.y, b1.z, b1.w};
  bfrag r;
#pragma unroll
  for (int i = 0; i < 8; i++) r.u[i] = f2bf((x[i] - mean) * rstd * gv[i] + bv[i]);
  *(uint4*)(o + base) = r.q;
}

// ---------------- fused double layernorm, wave-per-row ----------------------
__global__ __launch_bounds__(256)
void ln2x_kernel(const u16* __restrict__ hin, const u16* __restrict__ y,
                 const float* __restrict__ g, const float* __restrict__ be,
                 u16* __restrict__ o16) {
  int wv = threadIdx.x >> 6, lane = threadIdx.x & 63;
  int row = blockIdx.x * 4 + wv;
  size_t base = (size_t)row * DM_ + lane * 8;
  bfrag hv; hv.q = *(const uint4*)(hin + base);
  bfrag yv; yv.q = *(const uint4*)(y + base);
  float4 g0 = *(const float4*)(g + lane * 8), g1 = *(const float4*)(g + lane * 8 + 4);
  float4 b0 = *(const float4*)(be + lane * 8), b1 = *(const float4*)(be + lane * 8 + 4);
  float gv[8] = {g0.x, g0.y, g0.z, g0.w, g1.x, g1.y, g1.z, g1.w};
  float bv[8] = {b0.x, b0.y, b0.z, b0.w, b1.x, b1.y, b1.z, b1.w};
  float x[8], yy[8], s = 0.f, ss = 0.f;
#pragma unroll
  for (int i = 0; i < 8; i++) {
    yy[i] = bf2f(yv.u[i]);
    x[i] = bf2f(hv.u[i]) + yy[i];
    s += x[i]; ss = fmaf(x[i], x[i], ss);
  }
#pragma unroll
  for (int off = 32; off >= 1; off >>= 1) { s += __shfl_xor(s, off, 64); ss += __shfl_xor(ss, off, 64); }
  float mean = s * (1.0f / DM_);
  float var = ss * (1.0f / DM_) - mean * mean;
  float rstd = rsqrtf(var + EPS_);
  float h2[8]; s = 0.f; ss = 0.f;
#pragma unroll
  for (int i = 0; i < 8; i++) {
    h2[i] = (x[i] - mean) * rstd * gv[i] + bv[i] + yy[i];
    s += h2[i]; ss = fmaf(h2[i], h2[i], ss);
  }
#pragma unroll
  for (int off = 32; off >= 1; off >>= 1) { s += __shfl_xor(s, off, 64); ss += __shfl_xor(ss, off, 64); }
  mean = s * (1.0f / DM_);
  var = ss * (1.0f / DM_) - mean * mean;
  rstd = rsqrtf(var + EPS_);
  bfrag r;
#pragma unroll
  for (int i = 0; i < 8; i++) r.u[i] = f2bf((h2[i] - mean) * rstd * gv[i] + bv[i]);
  *(uint4*)(o16 + base) = r.q;
}

// ---------------- final head (bf16 in) --------------------------------------
__global__ __launch_bounds__(512)
void final_kernel(const u16* __restrict__ h, const float* __restrict__ gn,
                  const float* __restrict__ bn, const float* __restrict__ fcw,
                  const float* __restrict__ fcb, float* __restrict__ out) {
  int b = blockIdx.x;
  int t = threadIdx.x;
  size_t base = ((size_t)b * L_ + (L_ - 1)) * DM_;
  float x = bf2f(h[base + t]);
  float s = wave_reduce_sum(x);
  float ss = wave_reduce_sum(x * x);
  __shared__ float sh_s[8], sh_ss[8];
  int wv = t >> 6, lane = t & 63;
  if (lane == 0) { sh_s[wv] = s; sh_ss[wv] = ss; }
  __syncthreads();
  float S = 0.f, SS = 0.f;
#pragma unroll
  for (int i = 0; i < 8; i++) { S += sh_s[i]; SS += sh_ss[i]; }
  float mean = S * (1.0f / DM_);
  float var = SS * (1.0f / DM_) - mean * mean;
  float rstd = rsqrtf(var + EPS_);
  __shared__ float hn[DM_];
  hn[t] = (x - mean) * rstd * gn[t] + bn[t];
  __syncthreads();
  if (t < PRED_) {
    float acc = fcb[t];
#pragma unroll 8
    for (int d = 0; d < DM_; d++) acc = fmaf(hn[d], fcw[d * PRED_ + t], acc);
    out[b * PRED_ + t] = acc;
  }
}

// ---------------- driver ----------------
extern "C" void kernel_launch(void* const* d_in, const int* in_sizes, int n_in,
                              void* d_out, int out_size, void* d_ws, size_t ws_size,
                              hipStream_t stream) {
  const float* x     = (const float*)d_in[0];
  const float* emb_w = (const float*)d_in[1];
  const float* emb_b = (const float*)d_in[2];
  const float* pe    = (const float*)d_in[3];
  const float* Wq = (const float*)d_in[4];  const float* bq = (const float*)d_in[5];
  const float* Wk = (const float*)d_in[6];  const float* bk = (const float*)d_in[7];
  const float* Wv = (const float*)d_in[8];  const float* bv = (const float*)d_in[9];
  const float* Wo = (const float*)d_in[10]; const float* bo = (const float*)d_in[11];
  const float* W1 = (const float*)d_in[12]; const float* b1 = (const float*)d_in[13];
  const float* W2 = (const float*)d_in[14]; const float* b2 = (const float*)d_in[15];
  const float* g1 = (const float*)d_in[16]; const float* be1 = (const float*)d_in[17];
  const float* g2 = (const float*)d_in[18]; const float* be2 = (const float*)d_in[19];
  const float* lm_qw = (const float*)d_in[20]; const float* lm_qb = (const float*)d_in[21];
  const float* lm_kw = (const float*)d_in[22]; const float* lm_kb = (const float*)d_in[23];
  const float* gn = (const float*)d_in[24]; const float* bn = (const float*)d_in[25];
  const float* fc_w = (const float*)d_in[26]; const float* fc_b = (const float*)d_in[27];
  float* out = (float*)d_out;

  const size_t ROWS = (size_t)B_ * L_;     // 8000
  u16* qkv16 = (u16*)d_ws;                               // [8000][1792]
  u16* ctx16 = qkv16 + ROWS * QKVS;                      // [8000][512]
  u16* ffn1  = qkv16;                                    // [8000][2048] alias (qkv+ctx)
  u16* h16   = ctx16 + ROWS * DM_;                       // [8000][512]
  u16* t16   = h16 + ROWS * DM_;                         // [8000][512]
  u16* vtg   = t16 + ROWS * DM_;                         // [64][64][1024] dedicated
                                                         // (tail keys keep 0xAA poison =
                                                         //  finite bf16; P=0 -> safe)
  u16* Wqkv_t = vtg + (size_t)64 * 64 * 1024;            // [NL][1792][512]
  u16* Wo_t   = Wqkv_t + (size_t)NL_ * QKVS * DM_;       // [NL][512][512]
  u16* W1_t   = Wo_t + (size_t)NL_ * DM_ * DM_;          // [NL][2048][512]
  u16* W2_t   = W1_t + (size_t)NL_ * DFF_ * DM_;         // [NL][512][2048]
  float* bqkv = (float*)(W2_t + (size_t)NL_ * DM_ * DFF_);

  transpose_w<<<dim3(16, 16, NL_), 256, 0, stream>>>(Wq, Wqkv_t, DM_, DM_, (size_t)DM_ * DM_, (size_t)QKVS * DM_, 0, DM_);
  transpose_w<<<dim3(16, 16, NL_), 256, 0, stream>>>(Wk, Wqkv_t, DM_, DM_, (size_t)DM_ * DM_, (size_t)QKVS * DM_, 512, DM_);
  transpose_w<<<dim3(16, 16, NL_), 256, 0, stream>>>(Wv, Wqkv_t, DM_, DM_, (size_t)DM_ * DM_, (size_t)QKVS * DM_, 1024, DM_);
  transpose_w<<<dim3(16, 16, NL_), 256, 0, stream>>>(Wo, Wo_t, DM_, DM_, (size_t)DM_ * DM_, (size_t)DM_ * DM_, 0, DM_);
  transpose_w<<<dim3(64, 16, NL_), 256, 0, stream>>>(W1, W1_t, DM_, DFF_, (size_t)DM_ * DFF_, (size_t)DFF_ * DM_, 0, DM_);
  transpose_w<<<dim3(16, 64, NL_), 256, 0, stream>>>(W2, W2_t, DFF_, DM_, (size_t)DFF_ * DM_, (size_t)DM_ * DFF_, 0, DFF_);
  wfuse_kernel<<<dim3(H_, 2, NL_), 256, 0, stream>>>(Wq, Wk, lm_qw, lm_kw, Wqkv_t);
  concat_bias<<<NL_ * QKVS / 256, 256, 0, stream>>>(bq, bk, bv, lm_qw, lm_qb, lm_kw, lm_kb, bqkv);

  embed_kernel<<<dim3((unsigned)ROWS), 512, 0, stream>>>(x, emb_w, emb_b, pe, h16);

  dim3 g_qkv(QKVS / 64, 125);    // (28, 125)
  dim3 g_ffn1(DFF_ / 64, 125);   // (32, 125)
  dim3 g_n512(DM_ / 64, 125);    // (8, 125)
  dim3 g_attn(1024);
  dim3 g_ln(2000);               // 4 rows/block, wave-per-row

  for (int i = 0; i < NL_; i++) {
    gemm64<64><<<g_qkv, 256, 0, stream>>>(h16, Wqkv_t + (size_t)i * QKVS * DM_,
        bqkv + i * QKVS, nullptr, qkv16, vtg, 8000, DM_, QKVS, 0, 512, C_QS);

    attn_mfma_kernel<<<g_attn, 256, 0, stream>>>(qkv16, vtg, ctx16);

    gemm64<64><<<g_n512, 256, 0, stream>>>(ctx16, Wo_t + (size_t)i * DM_ * DM_,
        bo + i * DM_, h16, t16, nullptr, 8000, DM_, DM_, 0, 0, 1.0f);
    ln_kernel<<<g_ln, 256, 0, stream>>>(t16, g1 + i * DM_, be1 + i * DM_, h16);

    gemm64<64><<<g_ffn1, 256, 0, stream>>>(h16, W1_t + (size_t)i * DFF_ * DM_,
        b1 + i * DFF_, nullptr, ffn1, nullptr, 8000, DM_, DFF_, 1, 0, 1.0f);
    gemm64<64><<<g_n512, 256, 0, stream>>>(ffn1, W2_t + (size_t)i * DM_ * DFF_,
        b2 + i * DM_, nullptr, t16, nullptr, 8000, DFF_, DM_, 0, 0, 1.0f);

    ln2x_kernel<<<g_ln, 256, 0, stream>>>(h16, t16, g2 + i * DM_, be2 + i * DM_, h16);
  }

  final_kernel<<<B_, 512, 0, stream>>>(h16, gn, bn, fc_w, fc_b, out);
}

// Round 12
// 1032.172 us; speedup vs baseline: 1.0099x; 1.0016x over previous
//
#include <hip/hip_runtime.h>
#include <math.h>

// Problem constants (PCUTransformer)
#define B_    8
#define L_    1000
#define F_    7
#define DM_   512
#define H_    8
#define DFF_  2048
#define NL_   4
#define PRED_ 50
#define DK_   64
#define P_    16
#define EPS_  1e-5f
#define QKVS  1792      // fused row: q(512) k(512) v-gap(512) qp(128) kp(128)

#define L2E_   1.4426950408889634f
#define C_QS   0.18033688011112042f   // 0.125 * log2(e) folded into q
#define BS_QP  2.8853900817779268f    // 2*log2(e) folded into fused qp weights
#define SHFT_  24.0f                  // fixed softmax shift (cancels in normalize)

typedef unsigned short u16;
typedef __bf16 bf16x8 __attribute__((ext_vector_type(8)));
typedef float  f32x4  __attribute__((ext_vector_type(4)));

// ---------------- helpers ----------------
__device__ inline float wave_reduce_sum(float x) {
#pragma unroll
  for (int off = 32; off >= 1; off >>= 1) x += __shfl_xor(x, off, 64);
  return x;
}
__device__ inline u16 f2bf(float f) {   // RNE float->bf16 bits
  unsigned int u = __float_as_uint(f);
  unsigned int r = u + 0x7FFFu + ((u >> 16) & 1u);
  return (u16)(r >> 16);
}
__device__ inline unsigned int pack2(float a, float b) {
  return (unsigned int)f2bf(a) | ((unsigned int)f2bf(b) << 16);
}
__device__ inline float bf2f(u16 u) { return __uint_as_float(((unsigned int)u) << 16); }
__device__ inline float fexp2(float x) { return __builtin_amdgcn_exp2f(x); }
__device__ inline float frcp(float x) { return __builtin_amdgcn_rcpf(x); }

union bfrag { bf16x8 b; uint4 q; u16 u[8]; };

// async global->LDS, 16B per lane; lds base wave-uniform, HW scatters lane*16
__device__ inline void gload16(const u16* g, u16* l) {
  __builtin_amdgcn_global_load_lds(
      (const __attribute__((address_space(1))) void*)g,
      (__attribute__((address_space(3))) void*)l, 16, 0, 0);
}

// ---------------- weight transpose-convert: out[n][k] = bf16(in[k][n]) ------
__global__ __launch_bounds__(256)
void transpose_w(const float* __restrict__ in, u16* __restrict__ out,
                 int K, int N, size_t in_lstride, size_t out_lstride,
                 int row_off, int out_ld) {
  __shared__ float tile[32][33];
  int z = blockIdx.z;
  int kk0 = blockIdx.y * 32, nn0 = blockIdx.x * 32;
  int tx = threadIdx.x & 31, ty = threadIdx.x >> 5;
  const float* ip = in + z * in_lstride;
  u16* op = out + z * out_lstride;
#pragma unroll
  for (int i = 0; i < 4; i++)
    tile[ty + i * 8][tx] = ip[(size_t)(kk0 + ty + i * 8) * N + nn0 + tx];
  __syncthreads();
#pragma unroll
  for (int i = 0; i < 4; i++)
    op[(size_t)(row_off + nn0 + ty + i * 8) * out_ld + kk0 + tx] = f2bf(tile[tx][ty + i * 8]);
}

// ---------------- fused lm weights: Wt rows 1536+side*128+hh*16+p -----------
__global__ __launch_bounds__(256)
void wfuse_kernel(const float* __restrict__ Wq, const float* __restrict__ Wk,
                  const float* __restrict__ lmqw, const float* __restrict__ lmkw,
                  u16* __restrict__ Wt) {
  int hh = blockIdx.x, side = blockIdx.y, layer = blockIdx.z;
  const float* W = (side ? Wk : Wq) + (size_t)layer * 512 * 512;
  const float* lw = side ? lmkw : lmqw;
  float scale = side ? 1.0f : BS_QP;
  __shared__ float lws[64][17];
  int t = threadIdx.x;
  for (int i = t; i < 1024; i += 256) lws[i >> 4][i & 15] = lw[i];
  __syncthreads();
  int p = t & 15, kk = t >> 4;
  u16* orow = Wt + (size_t)layer * QKVS * 512 + (size_t)(1536 + side * 128 + hh * 16 + p) * 512;
  for (int kb = 0; kb < 32; kb++) {
    int k = kb * 16 + kk;
    const float* wr = W + (size_t)k * 512 + hh * 64;
    float acc = 0.f;
#pragma unroll
    for (int d = 0; d < 64; d++) acc = fmaf(wr[d], lws[d][p], acc);
    orow[k] = f2bf(acc * scale);
  }
}

// ---------------- bias assembly: [NL][1792] ---------------------------------
__global__ __launch_bounds__(256)
void concat_bias(const float* __restrict__ bq, const float* __restrict__ bk,
                 const float* __restrict__ bv,
                 const float* __restrict__ lmqw, const float* __restrict__ lmqb,
                 const float* __restrict__ lmkw, const float* __restrict__ lmkb,
                 float* __restrict__ bqkv) {
  int i = blockIdx.x * 256 + threadIdx.x;   // NL*1792
  int l = i / QKVS, j = i % QKVS;
  float v;
  if (j < 512) v = bq[l * 512 + j];
  else if (j < 1024) v = bk[l * 512 + j - 512];
  else if (j < 1536) v = bv[l * 512 + j - 1024];
  else if (j < 1664) {
    int hh = (j - 1536) >> 4, p = (j - 1536) & 15;
    float acc = lmqb[p];
#pragma unroll
    for (int d = 0; d < 64; d++) acc = fmaf(bq[l * 512 + hh * 64 + d], lmqw[d * 16 + p], acc);
    v = acc * BS_QP;
  } else {
    int hh = (j - 1664) >> 4, p = (j - 1664) & 15;
    float acc = lmkb[p];
#pragma unroll
    for (int d = 0; d < 64; d++) acc = fmaf(bk[l * 512 + hh * 64 + d], lmkw[d * 16 + p], acc);
    v = acc;
  }
  bqkv[i] = v;
}

// ---------------- embedding (bf16 out) --------------------------------------
__global__ __launch_bounds__(512)
void embed_kernel(const float* __restrict__ x, const float* __restrict__ emb_w,
                  const float* __restrict__ emb_b, const float* __restrict__ pe,
                  u16* __restrict__ h16) {
  int bl = blockIdx.x;
  int l = bl % L_;
  int d = threadIdx.x;
  const float* xr = x + (size_t)bl * F_;
  float acc = emb_b[d] + pe[(size_t)l * DM_ + d];
#pragma unroll
  for (int f = 0; f < F_; f++) acc = fmaf(xr[f], emb_w[f * DM_ + d], acc);
  h16[(size_t)bl * DM_ + d] = f2bf(acc);
}

// ---------------- bf16 MFMA GEMM, BM=64, BN=64, BK=32, LDS dbuf -------------
// R12: R11 (BN=64) was EXACTLY neutral vs R9 (BN=128) because both were
// VGPR-capped, not LDS-capped: VGPR_Count=80 -> floor(512/80)=6 waves/SIMD =
// 6 blocks/CU in both configs. __launch_bounds__(256, 8) forces VGPR<=64 ->
// 8 blocks/CU (LDS 16KB admits 10). Live state ~55-60 VGPR, should fit; the
// spill tripwire is WRITE_SIZE ballooning (R2 signature) -> revert if seen.
template<int BN>
__global__ __launch_bounds__(256, 8)
void gemm64(const u16* __restrict__ A, const u16* __restrict__ Bt,
            const float* __restrict__ bias, const u16* __restrict__ resid,
            u16* __restrict__ C16, u16* __restrict__ vtg,
            int M, int K, int N, int relu, int nscale, float sval) {
  constexpr int NTW = BN / 32;
  constexpr int BG  = BN / 64;          // B gloads per wave (64->1)
  constexpr int ASZ = 32 * 64;          // 32 lines of 128B = 4KB per buffer
  constexpr int BSZ = (BN / 2) * 64;
  __shared__ u16 As[2 * ASZ];
  __shared__ u16 Bs[2 * BSZ];
  int t = threadIdx.x;
  int w = t >> 6, lane = t & 63;
  int wr = w >> 1, wc = w & 1;
  int mloc = lane & 15, quad = lane >> 4;
  int m0 = blockIdx.y * 64, n0 = blockIdx.x * BN;

  // staging: line R slot s holds chunk c=s^(R&7) -> global row 2R+(c>>2),
  // k-cols (c&3)*8..+8. Global addr carries the swizzle; LDS dest linear.
  const u16* agp; u16* alds;
  {
    int R = w * 8 + (lane >> 3);               // A line 0..31
    int c = (lane & 7) ^ (R & 7);
    int gm = m0 + 2 * R + (c >> 2); if (gm > M - 1) gm = M - 1;
    agp = A + (size_t)gm * K + (c & 3) * 8;
    alds = As + (w * 8) * 64;
  }
  const u16* bgp[BG]; u16* blds[BG];
#pragma unroll
  for (int j = 0; j < BG; j++) {
    int R = w * (8 * BG) + j * 8 + (lane >> 3); // B line 0..BN/2-1
    int c = (lane & 7) ^ (R & 7);
    bgp[j] = Bt + (size_t)(n0 + 2 * R + (c >> 2)) * K + (c & 3) * 8;
    blds[j] = Bs + (w * (8 * BG) + j * 8) * 64;
  }
  // fragment read: row tr, k-chunk quad -> line tr>>1, chunk (tr&1)*4+quad
  const u16* apt[2];
#pragma unroll
  for (int mi = 0; mi < 2; mi++) {
    int tr = wr * 32 + mi * 16 + mloc;
    int R = tr >> 1, c = (tr & 1) * 4 + quad;
    apt[mi] = As + R * 64 + ((c ^ (R & 7)) * 8);
  }
  const u16* bpt[NTW];
#pragma unroll
  for (int nt = 0; nt < NTW; nt++) {
    int tr = wc * (BN / 2) + nt * 16 + mloc;
    int R = tr >> 1, c = (tr & 1) * 4 + quad;
    bpt[nt] = Bs + R * 64 + ((c ^ (R & 7)) * 8);
  }

  f32x4 acc[2][NTW];
#pragma unroll
  for (int mi = 0; mi < 2; mi++)
#pragma unroll
    for (int nt = 0; nt < NTW; nt++) acc[mi][nt] = (f32x4){0.f, 0.f, 0.f, 0.f};

  // prologue: stage K-slab 0 into buffer 0
  gload16(agp, alds);
#pragma unroll
  for (int j = 0; j < BG; j++) gload16(bgp[j], blds[j]);
  __syncthreads();

  const int nk = K >> 5;
  int cur = 0;
  for (int tt = 0; tt < nk; ++tt) {
    if (tt + 1 < nk) {               // prefetch next slab; flies during compute
      const int nxt = cur ^ 1;
      const int koff = (tt + 1) * 32;
      gload16(agp + koff, alds + nxt * ASZ);
#pragma unroll
      for (int j = 0; j < BG; j++) gload16(bgp[j] + koff, blds[j] + nxt * BSZ);
    }
    const int ao = cur * ASZ, bo = cur * BSZ;
    bf16x8 af[2], bv[NTW];
#pragma unroll
    for (int mi = 0; mi < 2; mi++) af[mi] = *(const bf16x8*)(apt[mi] + ao);
#pragma unroll
    for (int nt = 0; nt < NTW; nt++) bv[nt] = *(const bf16x8*)(bpt[nt] + bo);
#pragma unroll
    for (int mi = 0; mi < 2; mi++)
#pragma unroll
      for (int nt = 0; nt < NTW; nt++)
        acc[mi][nt] = __builtin_amdgcn_mfma_f32_16x16x32_bf16(af[mi], bv[nt], acc[mi][nt], 0, 0, 0);
    if (tt + 1 < nk) __syncthreads(); // drains prefetch (post-compute)
    cur ^= 1;
  }

#pragma unroll
  for (int mi = 0; mi < 2; mi++) {
    int m_r0 = m0 + wr * 32 + mi * 16 + quad * 4;   // 4-aligned; 1000%4==0
#pragma unroll
    for (int nt = 0; nt < NTW; nt++) {
      int nbase = n0 + wc * (BN / 2) + nt * 16;     // wave-uniform region
      int n = nbase + mloc;
      if (vtg && nbase >= 1024 && nbase < 1536) {
        if (m_r0 < M) {                              // full 4-run valid (M%4==0)
          int bb = (m_r0 * 67109) >> 26;             // m/1000 for m<8000
          int ll = m_r0 - bb * 1000;
          int hh2 = (n - 1024) >> 6, dk = n & 63;
          float bn_ = bias[n];
          union { uint2 d; u16 s[4]; } pk;
#pragma unroll
          for (int r = 0; r < 4; r++) pk.s[r] = f2bf(acc[mi][nt][r] + bn_);
          u16* dst = vtg + ((size_t)(bb * 8 + hh2) * 64 + dk) * 1024 + ll;
          *(uint2*)dst = pk.d;                       // ll%4==0 -> 8B aligned
        }
      } else {
        float bn_ = bias[n];
#pragma unroll
        for (int r = 0; r < 4; r++) {
          int m = m_r0 + r;
          if (m >= M) continue;
          size_t crow = (size_t)m * N;
          float vsum = acc[mi][nt][r] + bn_;
          if (resid) vsum += bf2f(resid[crow + n]);
          if (n < nscale) vsum *= sval;
          if (relu) vsum = fmaxf(vsum, 0.f);
          C16[crow + n] = f2bf(vsum);
        }
      }
    }
  }
}

// ---------------- MFMA flash attention (R4 version: PARKED at best) ---------
// Three structures measured: R4 2-barrier+Ps-LDS = 56.2-57.1; R5 in-reg-shfl
// = 58.6; R10 dbuf+Kp-from-global = 63.0. R4 wins; floor is the softmax
// trans-op chain. Parked permanently.
#define KT   64
#define KPLD 24    // Kp row stride (48B)
#define PSLD 40    // per-wave P chunk row stride (16x32 tile)
__global__ __launch_bounds__(256)
void attn_mfma_kernel(const u16* __restrict__ qkv, const u16* __restrict__ vtg,
                      u16* __restrict__ ctx) {
  __shared__ u16 Ks[KT * 64];          // 8192B [key][dk], 8-chunk XOR
  __shared__ u16 Vt[64 * KT];          // 8192B [dk][key], 8-chunk XOR
  __shared__ u16 Kp[KT * KPLD];        // 3072B [key][p 0..15]
  __shared__ u16 Ps[4 * 16 * PSLD];    // 5120B per-wave P[16][32]

  // XCD swizzle: all 16 q-tiles of one (b,h) share linear%8 -> same XCD L2
  int Lid = blockIdx.x;                // 0..1023
  int qt = Lid >> 6;
  int bh = ((Lid & 7) << 3) | ((Lid >> 3) & 7);
  int b = bh >> 3, hh = bh & 7;
  int l0 = qt * 64;
  int t = threadIdx.x;
  int wv = t >> 6, lane = t & 63;
  int m = lane & 15, quad = lane >> 4;

  // Q (pre-scaled by 0.125*log2e) + fused qp (pre-scaled by 2*log2e)
  int lq = l0 + wv * 16 + m; if (lq > L_ - 1) lq = L_ - 1;
  const u16* qrow = qkv + (size_t)(b * L_ + lq) * QKVS + hh * DK_;
  bf16x8 qa0 = *(const bf16x8*)(qrow + quad * 8);
  bf16x8 qa1 = *(const bf16x8*)(qrow + 32 + quad * 8);
  bfrag qpa;
  if (quad < 2) {
    qpa.q = *(const uint4*)(qkv + (size_t)(b * L_ + lq) * QKVS + 1536 + hh * P_ + quad * 8);
  } else {
    qpa.q = make_uint4(0u, 0u, 0u, 0u);
  }

  // staging: slot s of row r holds chunk s^(r&7); 8 rows/wave/round, 2 rounds
  const u16* ks_g = qkv + ((size_t)b * L_ + (t >> 3)) * QKVS + 512 + hh * DK_
                    + ((t & 7) ^ ((t >> 3) & 7)) * 8;
  u16* ks_l = Ks + (t >> 6) * 512;
  const u16* vt_g = vtg + ((size_t)bh * DK_ + (t >> 3)) * 1024
                    + ((t & 7) ^ ((t >> 3) & 7)) * 8;
  u16* vt_l = Vt + (t >> 6) * 512;

  f32x4 O[4];
#pragma unroll
  for (int nt = 0; nt < 4; nt++) O[nt] = (f32x4){0.f, 0.f, 0.f, 0.f};
  float lrun[4] = {0.f, 0.f, 0.f, 0.f};

  u16* pw = Ps + wv * (16 * PSLD);
  const u16* pr0 = pw + m * PSLD + quad * 8;
  const f32x4 zz = (f32x4){0.f, 0.f, 0.f, 0.f};

  for (int s0 = 0; s0 < L_; s0 += KT) {
    uint4 p0, p1;
    if (t < KT) {
      int sg2 = s0 + t; if (sg2 > L_ - 1) sg2 = L_ - 1;
      const u16* pr = qkv + (size_t)(b * L_ + sg2) * QKVS + 1664 + hh * P_;
      p0 = *(const uint4*)(pr);
      p1 = *(const uint4*)(pr + 8);
    }
    __syncthreads();   // B1: prev-tile Ks/Vt/Kp reads done
#pragma unroll
    for (int j = 0; j < 2; j++) {
      gload16(ks_g + ((size_t)s0 + j * 32) * QKVS, ks_l + j * 2048);
      gload16(vt_g + s0 + (size_t)j * 32 * 1024, vt_l + j * 2048);
    }
    if (t < KT) {
      *(uint4*)&Kp[t * KPLD]     = p0;
      *(uint4*)&Kp[t * KPLD + 8] = p1;
    }
    __syncthreads();   // B2: tile staged

#pragma unroll
    for (int kc = 0; kc < 2; kc++) {
      float pv2[2][4];
#pragma unroll
      for (int h2 = 0; h2 < 2; h2++) {
        int nt = kc * 2 + h2;
        const u16* kb = Ks + (nt * 16 + m) * 64;
        int x0 = ((quad) ^ (m & 7)) * 8;
        int x1 = ((4 + quad) ^ (m & 7)) * 8;
        __builtin_amdgcn_s_setprio(1);
        f32x4 sacc = __builtin_amdgcn_mfma_f32_16x16x32_bf16(qa0, *(const bf16x8*)(kb + x0), zz, 0, 0, 0);
        sacc = __builtin_amdgcn_mfma_f32_16x16x32_bf16(qa1, *(const bf16x8*)(kb + x1), sacc, 0, 0, 0);
        bf16x8 kpf = *(const bf16x8*)(Kp + (nt * 16 + m) * KPLD + (quad & 1) * 8);
        f32x4 macc = __builtin_amdgcn_mfma_f32_16x16x32_bf16(qpa.b, kpf, zz, 0, 0, 0);
        __builtin_amdgcn_s_setprio(0);
        bool oob = (s0 + nt * 16 + m) >= L_;
#pragma unroll
        for (int r = 0; r < 4; r++) {
          float e = fexp2(macc[r]);                 // macc = 2*log2e*x
          float d = frcp(e + 1.f);
          float th = fmaf(d, -2.f * L2E_, L2E_);    // log2e*tanh(x)
          float s = sacc[r] + th;
          if (oob) s = -3e38f;
          float p = fexp2(s - SHFT_);
          pv2[h2][r] = p;
          lrun[r] += p;
        }
      }
      // P chunk: C-layout -> per-wave 16x32 LDS -> A-layout (same wave)
#pragma unroll
      for (int h2 = 0; h2 < 2; h2++)
#pragma unroll
        for (int r = 0; r < 4; r++)
          pw[(quad * 4 + r) * PSLD + h2 * 16 + m] = f2bf(pv2[h2][r]);
      bf16x8 pa = *(const bf16x8*)pr0;
      __builtin_amdgcn_s_setprio(1);
#pragma unroll
      for (int ntd = 0; ntd < 4; ntd++) {
        const u16* vb = Vt + (ntd * 16 + m) * KT + (((kc * 4 + quad) ^ (m & 7)) * 8);
        O[ntd] = __builtin_amdgcn_mfma_f32_16x16x32_bf16(pa, *(const bf16x8*)vb, O[ntd], 0, 0, 0);
      }
      __builtin_amdgcn_s_setprio(0);
    }
  }

  float inv[4];
#pragma unroll
  for (int r = 0; r < 4; r++) {
#pragma unroll
    for (int msk = 1; msk < 16; msk <<= 1) lrun[r] += __shfl_xor(lrun[r], msk, 64);
    inv[r] = frcp(lrun[r]);
  }
#pragma unroll
  for (int r = 0; r < 4; r++) {
    int l = l0 + wv * 16 + quad * 4 + r;
    if (l >= L_) continue;
    u16* crow = ctx + ((size_t)(b * L_ + l)) * DM_ + hh * DK_;
#pragma unroll
    for (int nt = 0; nt < 4; nt++) crow[nt * 16 + m] = f2bf(O[nt][r] * inv[r]);
  }
}

// ---------------- layernorm, one WAVE per row (no LDS, no barriers) ---------
__global__ __launch_bounds__(256)
void ln_kernel(const u16* __restrict__ a, const float* __restrict__ g,
               const float* __restrict__ be, u16* __restrict__ o) {
  int wv = threadIdx.x >> 6, lane = threadIdx.x & 63;
  int row = blockIdx.x * 4 + wv;
  size_t base = (size_t)row * DM_ + lane * 8;
  bfrag v; v.q = *(const uint4*)(a + base);
  float x[8], s = 0.f, ss = 0.f;
#pragma unroll
  for (int i = 0; i < 8; i++) { x[i] = bf2f(v.u[i]); s += x[i]; ss = fmaf(x[i], x[i], ss); }
#pragma unroll
  for (int off = 32; off >= 1; off >>= 1) { s += __shfl_xor(s, off, 64); ss += __shfl_xor(ss, off, 64); }
  float mean = s * (1.0f / DM_);
  float var = ss * (1.0f / DM_) - mean * mean;
  float rstd = rsqrtf(var + EPS_);
  float4 g0 = *(const float4*)(g + lane * 8), g1 = *(const float4*)(g + lane * 8 + 4);
  float4 b0 = *(const float4*)(be + lane * 8), b1 = *(const float4*)(be + lane * 8 + 4);
  float gv[8] = {g0.x, g0.y, g0.z, g0.w, g1.x, g1.y, g1.z, g1.w};
  float bv[8] = {b0.x, b0.y, b0.z, b0.w, b1.x, b1.y, b1.z, b1.w};
  bfrag r;
#pragma unroll
  for (int i = 0; i < 8; i++) r.u[i] = f2bf((x[i] - mean) * rstd * gv[i] + bv[i]);
  *(uint4*)(o + base) = r.q;
}

// ---------------- fused double layernorm, wave-per-row ----------------------
__global__ __launch_bounds__(256)
void ln2x_kernel(const u16* __restrict__ hin, const u16* __restrict__ y,
                 const float* __restrict__ g, const float* __restrict__ be,
                 u16* __restrict__ o16) {
  int wv = threadIdx.x >> 6, lane = threadIdx.x & 63;
  int row = blockIdx.x * 4 + wv;
  size_t base = (size_t)row * DM_ + lane * 8;
  bfrag hv; hv.q = *(const uint4*)(hin + base);
  bfrag yv; yv.q = *(const uint4*)(y + base);
  float4 g0 = *(const float4*)(g + lane * 8), g1 = *(const float4*)(g + lane * 8 + 4);
  float4 b0 = *(const float4*)(be + lane * 8), b1 = *(const float4*)(be + lane * 8 + 4);
  float gv[8] = {g0.x, g0.y, g0.z, g0.w, g1.x, g1.y, g1.z, g1.w};
  float bv[8] = {b0.x, b0.y, b0.z, b0.w, b1.x, b1.y, b1.z, b1.w};
  float x[8], yy[8], s = 0.f, ss = 0.f;
#pragma unroll
  for (int i = 0; i < 8; i++) {
    yy[i] = bf2f(yv.u[i]);
    x[i] = bf2f(hv.u[i]) + yy[i];
    s += x[i]; ss = fmaf(x[i], x[i], ss);
  }
#pragma unroll
  for (int off = 32; off >= 1; off >>= 1) { s += __shfl_xor(s, off, 64); ss += __shfl_xor(ss, off, 64); }
  float mean = s * (1.0f / DM_);
  float var = ss * (1.0f / DM_) - mean * mean;
  float rstd = rsqrtf(var + EPS_);
  float h2[8]; s = 0.f; ss = 0.f;
#pragma unroll
  for (int i = 0; i < 8; i++) {
    h2[i] = (x[i] - mean) * rstd * gv[i] + bv[i] + yy[i];
    s += h2[i]; ss = fmaf(h2[i], h2[i], ss);
  }
#pragma unroll
  for (int off = 32; off >= 1; off >>= 1) { s += __shfl_xor(s, off, 64); ss += __shfl_xor(ss, off, 64); }
  mean = s * (1.0f / DM_);
  var = ss * (1.0f / DM_) - mean * mean;
  rstd = rsqrtf(var + EPS_);
  bfrag r;
#pragma unroll
  for (int i = 0; i < 8; i++) r.u[i] = f2bf((h2[i] - mean) * rstd * gv[i] + bv[i]);
  *(uint4*)(o16 + base) = r.q;
}

// ---------------- final head (bf16 in) --------------------------------------
__global__ __launch_bounds__(512)
void final_kernel(const u16* __restrict__ h, const float* __restrict__ gn,
                  const float* __restrict__ bn, const float* __restrict__ fcw,
                  const float* __restrict__ fcb, float* __restrict__ out) {
  int b = blockIdx.x;
  int t = threadIdx.x;
  size_t base = ((size_t)b * L_ + (L_ - 1)) * DM_;
  float x = bf2f(h[base + t]);
  float s = wave_reduce_sum(x);
  float ss = wave_reduce_sum(x * x);
  __shared__ float sh_s[8], sh_ss[8];
  int wv = t >> 6, lane = t & 63;
  if (lane == 0) { sh_s[wv] = s; sh_ss[wv] = ss; }
  __syncthreads();
  float S = 0.f, SS = 0.f;
#pragma unroll
  for (int i = 0; i < 8; i++) { S += sh_s[i]; SS += sh_ss[i]; }
  float mean = S * (1.0f / DM_);
  float var = SS * (1.0f / DM_) - mean * mean;
  float rstd = rsqrtf(var + EPS_);
  __shared__ float hn[DM_];
  hn[t] = (x - mean) * rstd * gn[t] + bn[t];
  __syncthreads();
  if (t < PRED_) {
    float acc = fcb[t];
#pragma unroll 8
    for (int d = 0; d < DM_; d++) acc = fmaf(hn[d], fcw[d * PRED_ + t], acc);
    out[b * PRED_ + t] = acc;
  }
}

// ---------------- driver ----------------
extern "C" void kernel_launch(void* const* d_in, const int* in_sizes, int n_in,
                              void* d_out, int out_size, void* d_ws, size_t ws_size,
                              hipStream_t stream) {
  const float* x     = (const float*)d_in[0];
  const float* emb_w = (const float*)d_in[1];
  const float* emb_b = (const float*)d_in[2];
  const float* pe    = (const float*)d_in[3];
  const float* Wq = (const float*)d_in[4];  const float* bq = (const float*)d_in[5];
  const float* Wk = (const float*)d_in[6];  const float* bk = (const float*)d_in[7];
  const float* Wv = (const float*)d_in[8];  const float* bv = (const float*)d_in[9];
  const float* Wo = (const float*)d_in[10]; const float* bo = (const float*)d_in[11];
  const float* W1 = (const float*)d_in[12]; const float* b1 = (const float*)d_in[13];
  const float* W2 = (const float*)d_in[14]; const float* b2 = (const float*)d_in[15];
  const float* g1 = (const float*)d_in[16]; const float* be1 = (const float*)d_in[17];
  const float* g2 = (const float*)d_in[18]; const float* be2 = (const float*)d_in[19];
  const float* lm_qw = (const float*)d_in[20]; const float* lm_qb = (const float*)d_in[21];
  const float* lm_kw = (const float*)d_in[22]; const float* lm_kb = (const float*)d_in[23];
  const float* gn = (const float*)d_in[24]; const float* bn = (const float*)d_in[25];
  const float* fc_w = (const float*)d_in[26]; const float* fc_b = (const float*)d_in[27];
  float* out = (float*)d_out;

  const size_t ROWS = (size_t)B_ * L_;     // 8000
  u16* qkv16 = (u16*)d_ws;                               // [8000][1792]
  u16* ctx16 = qkv16 + ROWS * QKVS;                      // [8000][512]
  u16* ffn1  = qkv16;                                    // [8000][2048] alias (qkv+ctx)
  u16* h16   = ctx16 + ROWS * DM_;                       // [8000][512]
  u16* t16   = h16 + ROWS * DM_;                         // [8000][512]
  u16* vtg   = t16 + ROWS * DM_;                         // [64][64][1024] dedicated
                                                         // (tail keys keep 0xAA poison =
                                                         //  finite bf16; P=0 -> safe)
  u16* Wqkv_t = vtg + (size_t)64 * 64 * 1024;            // [NL][1792][512]
  u16* Wo_t   = Wqkv_t + (size_t)NL_ * QKVS * DM_;       // [NL][512][512]
  u16* W1_t   = Wo_t + (size_t)NL_ * DM_ * DM_;          // [NL][2048][512]
  u16* W2_t   = W1_t + (size_t)NL_ * DFF_ * DM_;         // [NL][512][2048]
  float* bqkv = (float*)(W2_t + (size_t)NL_ * DM_ * DFF_);

  transpose_w<<<dim3(16, 16, NL_), 256, 0, stream>>>(Wq, Wqkv_t, DM_, DM_, (size_t)DM_ * DM_, (size_t)QKVS * DM_, 0, DM_);
  transpose_w<<<dim3(16, 16, NL_), 256, 0, stream>>>(Wk, Wqkv_t, DM_, DM_, (size_t)DM_ * DM_, (size_t)QKVS * DM_, 512, DM_);
  transpose_w<<<dim3(16, 16, NL_), 256, 0, stream>>>(Wv, Wqkv_t, DM_, DM_, (size_t)DM_ * DM_, (size_t)QKVS * DM_, 1024, DM_);
  transpose_w<<<dim3(16, 16, NL_), 256, 0, stream>>>(Wo, Wo_t, DM_, DM_, (size_t)DM_ * DM_, (size_t)DM_ * DM_, 0, DM_);
  transpose_w<<<dim3(64, 16, NL_), 256, 0, stream>>>(W1, W1_t, DM_, DFF_, (size_t)DM_ * DFF_, (size_t)DFF_ * DM_, 0, DM_);
  transpose_w<<<dim3(16, 64, NL_), 256, 0, stream>>>(W2, W2_t, DFF_, DM_, (size_t)DFF_ * DM_, (size_t)DM_ * DFF_, 0, DFF_);
  wfuse_kernel<<<dim3(H_, 2, NL_), 256, 0, stream>>>(Wq, Wk, lm_qw, lm_kw, Wqkv_t);
  concat_bias<<<NL_ * QKVS / 256, 256, 0, stream>>>(bq, bk, bv, lm_qw, lm_qb, lm_kw, lm_kb, bqkv);

  embed_kernel<<<dim3((unsigned)ROWS), 512, 0, stream>>>(x, emb_w, emb_b, pe, h16);

  dim3 g_qkv(QKVS / 64, 125);    // (28, 125)
  dim3 g_ffn1(DFF_ / 64, 125);   // (32, 125)
  dim3 g_n512(DM_ / 64, 125);    // (8, 125)
  dim3 g_attn(1024);
  dim3 g_ln(2000);               // 4 rows/block, wave-per-row

  for (int i = 0; i < NL_; i++) {
    gemm64<64><<<g_qkv, 256, 0, stream>>>(h16, Wqkv_t + (size_t)i * QKVS * DM_,
        bqkv + i * QKVS, nullptr, qkv16, vtg, 8000, DM_, QKVS, 0, 512, C_QS);

    attn_mfma_kernel<<<g_attn, 256, 0, stream>>>(qkv16, vtg, ctx16);

    gemm64<64><<<g_n512, 256, 0, stream>>>(ctx16, Wo_t + (size_t)i * DM_ * DM_,
        bo + i * DM_, h16, t16, nullptr, 8000, DM_, DM_, 0, 0, 1.0f);
    ln_kernel<<<g_ln, 256, 0, stream>>>(t16, g1 + i * DM_, be1 + i * DM_, h16);

    gemm64<64><<<g_ffn1, 256, 0, stream>>>(h16, W1_t + (size_t)i * DFF_ * DM_,
        b1 + i * DFF_, nullptr, ffn1, nullptr, 8000, DM_, DFF_, 1, 0, 1.0f);
    gemm64<64><<<g_n512, 256, 0, stream>>>(ffn1, W2_t + (size_t)i * DM_ * DFF_,
        b2 + i * DM_, nullptr, t16, nullptr, 8000, DFF_, DM_, 0, 0, 1.0f);

    ln2x_kernel<<<g_ln, 256, 0, stream>>>(h16, t16, g2 + i * DM_, be2 + i * DM_, h16);
  }

  final_kernel<<<B_, 512, 0, stream>>>(h16, gn, bn, fc_w, fc_b, out);
}